// Round 2
// baseline (799.694 us; speedup 1.0000x reference)
//
#include <hip/hip_runtime.h>
#include <math.h>

#define B_ 2048
#define H_ 16
#define KL_ 16
#define D_ 64
#define KMAX_ 32
#define DE_ 32
#define NK_ 32   // bank rows = KL+KR
#define KP_ 32   // k_parent (queries)

// ---------------- precompute: pq[32*64] and dv[32] into ws (fp32) -------------
__global__ void precompute_pq(const float* __restrict__ pqb,
                              const float* __restrict__ qow,
                              const float* __restrict__ qob,
                              const int* __restrict__ depth_p,
                              float* __restrict__ ws) {
    __shared__ float dvS[DE_];
    const int t = threadIdx.x;
    const int depth = depth_p[0];
    if (t < DE_) {
        int pi_ = t >> 1;
        float inv = expf(-(float)(2 * pi_) * (logf(10000.f) / (float)DE_));
        float x = (float)depth * inv;
        dvS[t] = (t & 1) ? cosf(x) : sinf(x);
    }
    __syncthreads();
    int j = blockIdx.x * blockDim.x + t;           // 0..2047
    float acc = pqb[j] + qob[j];
    for (int i = 0; i < DE_; ++i)
        acc += dvS[i] * qow[i * (KMAX_ * D_) + j];
    ws[j] = acc;
    if (blockIdx.x == 0 && t < DE_) ws[KMAX_ * D_ + t] = dvS[t];
}

// ---------------- main: one block per (b,h) -------------
__global__ __launch_bounds__(256, 4)
void gwm_main(const float* __restrict__ fL, const float* __restrict__ fR,
              const float* __restrict__ glw, const float* __restrict__ glb,
              const float* __restrict__ grw, const float* __restrict__ grb,
              const float* __restrict__ lng, const float* __restrict__ lnb,
              const float* __restrict__ spw, const float* __restrict__ sa,
              const float* __restrict__ wf, const float* __restrict__ wd,
              const float* __restrict__ wp, const int* __restrict__ depth_p,
              const float* __restrict__ ws, float* __restrict__ out)
{
    __shared__ float bankS[NK_ * 65];   // padded stride 65 -> conflict-free
    __shared__ float pqS[KP_ * 65];
    __shared__ float attnS[KP_ * 33];
    __shared__ float lmS[D_], rmS[D_], glS[D_], grS[D_], skS[D_];
    __shared__ float gamS[D_], betS[D_], dvS[DE_];

    const int t = threadIdx.x;
    const int pair = blockIdx.x;        // b*H + h
    const int h = pair & (H_ - 1);
    const int depth = depth_p[0];

    // --- per-block constants ---
    {   // pq: 8 contiguous floats per thread into padded LDS (8 | 64 so same row)
        int j0 = t * 8;
        int row = j0 >> 6, col = j0 & 63;
        const float* src = ws + j0;
        float* dst = pqS + row * 65 + col;
        #pragma unroll
        for (int i = 0; i < 8; ++i) dst[i] = src[i];
    }
    if (t < DE_) dvS[t] = ws[KMAX_ * D_ + t];
    if (t < D_) { gamS[t] = lng[t]; betS[t] = lnb[t]; }

    // per-h phasor: decay = exp(-softplus(wd)); ang = wf + wp + depth*pi/4
    float wdv = wd[h];
    float sp = logf(1.f + expf(wdv));
    float decay = expf(-sp);
    float ang = wf[h] + wp[h] + (float)depth * 0.78539816339744831f;
    float pr  = decay * cosf(ang);
    float pim = decay * sinf(ang);
    float sigsa = 1.f / (1.f + expf(-sa[0]));

    // --- Phase A: f_left -> bank[0:16], rot(f_right) -> bank[16:32] ---
    const size_t baseL = (size_t)pair * (KL_ * D_);
    {
        int k = t >> 4, d0 = (t & 15) * 4;
        float4 v = *reinterpret_cast<const float4*>(fL + baseL + k * D_ + d0);
        float* dst = bankS + k * 65 + d0;
        dst[0] = v.x; dst[1] = v.y; dst[2] = v.z; dst[3] = v.w;
    }
    {
        int k = t >> 4, d0 = (t & 15) * 2;   // even, 0..30
        const float* p = fR + baseL + k * D_;
        float2 fr = *reinterpret_cast<const float2*>(p + d0);
        float2 fi = *reinterpret_cast<const float2*>(p + d0 + 32);
        float* dst = bankS + (16 + k) * 65;
        dst[d0]      = pr * fr.x - pim * fi.x;
        dst[d0 + 1]  = pr * fr.y - pim * fi.y;
        dst[d0 + 32] = pim * fr.x + pr * fi.x;
        dst[d0 + 33] = pim * fr.y + pr * fi.y;
    }
    __syncthreads();

    // --- Phase B: means over k ---
    if (t < 128) {
        int d = t & 63;
        int r0 = (t < 64) ? 0 : 16;
        float s = 0.f;
        #pragma unroll
        for (int k = 0; k < 16; ++k) s += bankS[(r0 + k) * 65 + d];
        s *= (1.f / 16.f);
        if (t < 64) lmS[d] = s; else rmS[d] = s;
    }
    __syncthreads();

    // --- Phase C: gates (waves 0,1) + skip projection (wave 2) ---
    if (t < 192) {
        int d = t & 63;
        if (t < 128) {
            const float* W  = (t < 64) ? glw : grw;
            const float* Bv = (t < 64) ? glb : grb;
            float acc = Bv[d];
            for (int i = 0; i < D_; ++i)  acc += lmS[i] * W[i * D_ + d];
            for (int i = 0; i < D_; ++i)  acc += rmS[i] * W[(D_ + i) * D_ + d];
            for (int i = 0; i < DE_; ++i) acc += dvS[i] * W[(2 * D_ + i) * D_ + d];
            float g = 1.f / (1.f + expf(-acc));
            if (t < 64) glS[d] = g; else grS[d] = g;
        } else {
            float acc = 0.f;
            for (int i = 0; i < D_; ++i) acc += lmS[i] * spw[i * D_ + d];
            skS[d] = acc;
        }
    }
    __syncthreads();

    // --- Phase D: scale bank by gates ---
    {
        int k = t >> 3, d0 = (t & 7) * 8;
        float* row = bankS + k * 65 + d0;
        const float* g = (k < 16) ? (glS + d0) : (grS + d0);
        #pragma unroll
        for (int j = 0; j < 8; ++j) row[j] *= g[j];
    }
    __syncthreads();

    // --- Phase E: scores (q x k) + softmax over k ---
    {
        int q = t >> 3, k0 = (t & 7) * 4;
        float s0 = 0, s1 = 0, s2 = 0, s3 = 0;
        const float* pqrow = pqS + q * 65;
        for (int d = 0; d < D_; ++d) {
            float p = pqrow[d];
            s0 += p * bankS[(k0 + 0) * 65 + d];
            s1 += p * bankS[(k0 + 1) * 65 + d];
            s2 += p * bankS[(k0 + 2) * 65 + d];
            s3 += p * bankS[(k0 + 3) * 65 + d];
        }
        s0 *= 0.125f; s1 *= 0.125f; s2 *= 0.125f; s3 *= 0.125f;
        float m = fmaxf(fmaxf(s0, s1), fmaxf(s2, s3));
        #pragma unroll
        for (int off = 1; off < 8; off <<= 1) m = fmaxf(m, __shfl_xor(m, off, 8));
        float e0 = __expf(s0 - m), e1 = __expf(s1 - m);
        float e2 = __expf(s2 - m), e3 = __expf(s3 - m);
        float ssum = e0 + e1 + e2 + e3;
        #pragma unroll
        for (int off = 1; off < 8; off <<= 1) ssum += __shfl_xor(ssum, off, 8);
        float inv = 1.f / ssum;
        float* arow = attnS + q * 33 + k0;
        arow[0] = e0 * inv; arow[1] = e1 * inv; arow[2] = e2 * inv; arow[3] = e3 * inv;
    }
    __syncthreads();

    // --- Phase F: parent = attn @ bank, layernorm, + skip, store fp32 ---
    {
        int q = t >> 3, d0 = (t & 7) * 8;
        float acc[8];
        #pragma unroll
        for (int j = 0; j < 8; ++j) acc[j] = 0.f;
        const float* arow = attnS + q * 33;
        for (int k = 0; k < NK_; ++k) {
            float a = arow[k];
            const float* brow = bankS + k * 65 + d0;
            #pragma unroll
            for (int j = 0; j < 8; ++j) acc[j] += a * brow[j];
        }
        float s = 0.f;
        #pragma unroll
        for (int j = 0; j < 8; ++j) s += acc[j];
        #pragma unroll
        for (int off = 1; off < 8; off <<= 1) s += __shfl_xor(s, off, 8);
        float mu = s * (1.f / 64.f);
        float ssd = 0.f;
        #pragma unroll
        for (int j = 0; j < 8; ++j) { float d = acc[j] - mu; ssd += d * d; }
        #pragma unroll
        for (int off = 1; off < 8; off <<= 1) ssd += __shfl_xor(ssd, off, 8);
        float var = ssd * (1.f / 64.f);
        float rinv = 1.f / sqrtf(var + 1e-5f);
        float o[8];
        #pragma unroll
        for (int j = 0; j < 8; ++j) {
            int d = d0 + j;
            o[j] = (acc[j] - mu) * rinv * gamS[d] + betS[d] + sigsa * skS[d];
        }
        float* dst = out + (size_t)pair * (KP_ * D_) + q * D_ + d0;
        *reinterpret_cast<float4*>(dst)     = make_float4(o[0], o[1], o[2], o[3]);
        *reinterpret_cast<float4*>(dst + 4) = make_float4(o[4], o[5], o[6], o[7]);
    }
}

extern "C" void kernel_launch(void* const* d_in, const int* in_sizes, int n_in,
                              void* d_out, int out_size, void* d_ws, size_t ws_size,
                              hipStream_t stream) {
    const float* fL  = (const float*)d_in[0];
    const float* fR  = (const float*)d_in[1];
    const float* glw = (const float*)d_in[2];
    const float* glb = (const float*)d_in[3];
    const float* grw = (const float*)d_in[4];
    const float* grb = (const float*)d_in[5];
    const float* pqb = (const float*)d_in[6];
    const float* qow = (const float*)d_in[7];
    const float* qob = (const float*)d_in[8];
    const float* lng = (const float*)d_in[9];
    const float* lnb = (const float*)d_in[10];
    const float* spw = (const float*)d_in[11];
    const float* sa  = (const float*)d_in[12];
    const float* wf  = (const float*)d_in[13];
    const float* wd  = (const float*)d_in[14];
    const float* wp  = (const float*)d_in[15];
    const int* depth = (const int*)d_in[16];
    float* ws = (float*)d_ws;
    float* out = (float*)d_out;

    hipLaunchKernelGGL(precompute_pq, dim3(8), dim3(256), 0, stream,
                       pqb, qow, qob, depth, ws);
    hipLaunchKernelGGL(gwm_main, dim3(B_ * H_), dim3(256), 0, stream,
                       fL, fR, glw, glb, grw, grb, lng, lnb, spw, sa,
                       wf, wd, wp, depth, ws, out);
}